// Round 9
// baseline (169.733 us; speedup 1.0000x reference)
//
#include <hip/hip_runtime.h>

// Problem constants (fixed by setup_inputs)
#define B_    8
#define D_    4
#define H_    640
#define W_    640
#define HW_   (H_ * W_)      // 409600
#define L_    8
#define NL    (L_ - 1)       // labels 1..7
#define BLOCK 256
#define VITER 2              // float4 iterations per thread -> 8 px/thread
#define PXB   (BLOCK * 4 * VITER)           // 2048 px per block
#define GRIDX (HW_ / PXB)                   // 200 -> grid (200,8) = 1600 blocks

__device__ __forceinline__ void gatom_add(float* p, float v) {
    unsafeAtomicAdd(p, v);   // global_atomic_add_f32
}

// ---------------------------------------------------------------------------
// ws layout (4-byte elements):
//   int   firstIdx [64] @0     int secondIdx[64] @64
//   int   cntf_i   [64] @128   int cntk_i   [64] @192
//   float sumemb  [256] @256   float sumvalb [8] @512
//   u32   lblpack  [409600] @1024   (8 x 4-bit labels per thread)
// ---------------------------------------------------------------------------
__global__ void k_init(int* ib) {
    int t = threadIdx.x;
    if (t < 128) ib[t] = HW_;        // firstIdx + secondIdx
    ib[128 + t] = 0;                 // 128..383
    if (t < 137) ib[384 + t] = 0;    // 384..520
}

// ---------------------------------------------------------------------------
// K1: counts, kernel-region sums, first+second occurrence, label export.
// MLP fix (R8 lesson): all 14 vec4 loads issued as straight-line code, then
// __builtin_amdgcn_sched_barrier(0) — scheduler cannot sink them to uses, so
// the wave has 14 loads in flight and drains vmcnt ONCE instead of 14 times.
// Hand-unrolled halves, no slot selects. launch_bounds(256,2): VGPR headroom.
// ---------------------------------------------------------------------------
__global__ __launch_bounds__(BLOCK, 2) void k_pass1(
        const float* __restrict__ emb, const int* __restrict__ inst,
        const float* __restrict__ kern, const float* __restrict__ tmask,
        int* __restrict__ firstIdx, int* __restrict__ secondIdx,
        int* __restrict__ cntf_i, int* __restrict__ cntk_i,
        float* __restrict__ sumemb, unsigned int* __restrict__ lblpack) {
    __shared__ int   sCnt[L_];       // cf<<16 | ck
    __shared__ float sSum[L_ * D_];
    __shared__ int   sM1[L_], sM2[L_];

    const int tid  = threadIdx.x;
    const int lane = tid & 63;
    if (tid < L_) { sCnt[tid] = 0; sM1[tid] = HW_; sM2[tid] = HW_; }
    if (tid < L_ * D_) sSum[tid] = 0.f;
    __syncthreads();

    const int b = blockIdx.y;
    const int blockbase = blockIdx.x * PXB;
    const float* embb = emb + (size_t)b * D_ * HW_;
    const int base = b * HW_;
    const int o0 = blockbase + tid * 4;
    const int o1 = o0 + BLOCK * 4;

    // ---- all 14 vec4 loads, straight-line ----
    const int4   lb0 = *(const int4*)  (inst  + base + o0);
    const int4   lb1 = *(const int4*)  (inst  + base + o1);
    const float4 tm0 = *(const float4*)(tmask + base + o0);
    const float4 tm1 = *(const float4*)(tmask + base + o1);
    const float4 kn0 = *(const float4*)(kern  + base + o0);
    const float4 kn1 = *(const float4*)(kern  + base + o1);
    const float4 e00 = *(const float4*)(embb + 0 * HW_ + o0);
    const float4 e01 = *(const float4*)(embb + 1 * HW_ + o0);
    const float4 e02 = *(const float4*)(embb + 2 * HW_ + o0);
    const float4 e03 = *(const float4*)(embb + 3 * HW_ + o0);
    const float4 e10 = *(const float4*)(embb + 0 * HW_ + o1);
    const float4 e11 = *(const float4*)(embb + 1 * HW_ + o1);
    const float4 e12 = *(const float4*)(embb + 2 * HW_ + o1);
    const float4 e13 = *(const float4*)(embb + 3 * HW_ + o1);
    __builtin_amdgcn_sched_barrier(0);   // loads stay above; one vmcnt drain

    float sm[NL][D_];
    #pragma unroll
    for (int l = 0; l < NL; ++l)
        #pragma unroll
        for (int d = 0; d < D_; ++d) sm[l][d] = 0.f;
    int bp0 = 0, bp1 = 0, bp2 = 0, km = 0;
    unsigned int lp = 0;

    {   // half 0: px = 0..3
        const int*   labA = (const int*)&lb0;
        const float* tmA  = (const float*)&tm0;
        const float* knA  = (const float*)&kn0;
        const float* e0A  = (const float*)&e00;
        const float* e1A  = (const float*)&e01;
        const float* e2A  = (const float*)&e02;
        const float* e3A  = (const float*)&e03;
        #pragma unroll
        for (int c = 0; c < 4; ++c) {
            const int px = c;
            const int lf  = (tmA[c] > 0.5f) ? labA[c] : 0;
            const bool kb = (knA[c] > 0.5f);
            const int lfk = kb ? lf : 0;
            bp0 |= (lf & 1) << px;
            bp1 |= ((lf >> 1) & 1) << px;
            bp2 |= ((lf >> 2) & 1) << px;
            km  |= (kb ? 1 : 0) << px;
            lp  |= (unsigned int)lf << (4 * px);
            #pragma unroll
            for (int l = 1; l < L_; ++l) {
                const float mk = (lfk == l) ? 1.0f : 0.0f;
                sm[l - 1][0] += mk * e0A[c];
                sm[l - 1][1] += mk * e1A[c];
                sm[l - 1][2] += mk * e2A[c];
                sm[l - 1][3] += mk * e3A[c];
            }
        }
    }
    {   // half 1: px = 4..7
        const int*   labA = (const int*)&lb1;
        const float* tmA  = (const float*)&tm1;
        const float* knA  = (const float*)&kn1;
        const float* e0A  = (const float*)&e10;
        const float* e1A  = (const float*)&e11;
        const float* e2A  = (const float*)&e12;
        const float* e3A  = (const float*)&e13;
        #pragma unroll
        for (int c = 0; c < 4; ++c) {
            const int px = 4 + c;
            const int lf  = (tmA[c] > 0.5f) ? labA[c] : 0;
            const bool kb = (knA[c] > 0.5f);
            const int lfk = kb ? lf : 0;
            bp0 |= (lf & 1) << px;
            bp1 |= ((lf >> 1) & 1) << px;
            bp2 |= ((lf >> 2) & 1) << px;
            km  |= (kb ? 1 : 0) << px;
            lp  |= (unsigned int)lf << (4 * px);
            #pragma unroll
            for (int l = 1; l < L_; ++l) {
                const float mk = (lfk == l) ? 1.0f : 0.0f;
                sm[l - 1][0] += mk * e0A[c];
                sm[l - 1][1] += mk * e1A[c];
                sm[l - 1][2] += mk * e2A[c];
                sm[l - 1][3] += mk * e3A[c];
            }
        }
    }

    // export packed labels for pass3 (same thread/block mapping there)
    lblpack[(size_t)(b * GRIDX + blockIdx.x) * BLOCK + tid] = lp;

    // ---- per-thread counts + first/second from bit-planes ----
    // pixel px of this thread: p = o0 + (px>>2)*BLOCK*4 + (px&3), monotone in px
    const int nb0 = ~bp0, nb1 = ~bp1, nb2 = ~bp2;
    int cnt[NL], m1[NL], m2[NL];
    #pragma unroll
    for (int l = 1; l < L_; ++l) {
        const int k = l - 1;
        int h = ((l & 1) ? bp0 : nb0) & ((l & 2) ? bp1 : nb1) & ((l & 4) ? bp2 : nb2);
        h &= 0xFF;
        cnt[k] = (__popc(h) << 16) | __popc(h & km);
        const int h2 = h & (h - 1);
        const int p1 = __ffs(h) - 1;      // valid only if h
        const int p2 = __ffs(h2) - 1;
        m1[k] = h  ? (o0 + (p1 >> 2) * (BLOCK * 4) + (p1 & 3)) : HW_;
        m2[k] = h2 ? (o0 + (p2 >> 2) * (BLOCK * 4) + (p2 & 3)) : HW_;
    }

    // ---- 64-lane butterfly (49 values, valid at lane 0) ----
    #pragma unroll
    for (int l = 0; l < NL; ++l) {
        #pragma unroll
        for (int off = 32; off > 0; off >>= 1) {
            cnt[l]   += __shfl_down(cnt[l], off);
            sm[l][0] += __shfl_down(sm[l][0], off);
            sm[l][1] += __shfl_down(sm[l][1], off);
            sm[l][2] += __shfl_down(sm[l][2], off);
            sm[l][3] += __shfl_down(sm[l][3], off);
            int o1v = __shfl_down(m1[l], off);
            int o2v = __shfl_down(m2[l], off);
            m2[l] = min(min(m2[l], o2v), max(m1[l], o1v));   // two-min combine
            m1[l] = min(m1[l], o1v);
        }
    }
    if (lane == 0) {
        #pragma unroll
        for (int l = 0; l < NL; ++l) {
            atomicAdd(&sCnt[l + 1], cnt[l]);   // fields <= 2048, no overflow
            #pragma unroll
            for (int d = 0; d < D_; ++d) atomicAdd(&sSum[(l + 1) * D_ + d], sm[l][d]);
            int old = atomicMin(&sM1[l + 1], m1[l]);
            atomicMin(&sM2[l + 1], max(old, m1[l]));
            atomicMin(&sM2[l + 1], m2[l]);
        }
    }
    __syncthreads();

    if (tid >= 1 && tid < L_) {
        const int pc = sCnt[tid];
        atomicAdd(&cntf_i[b * L_ + tid], pc >> 16);
        atomicAdd(&cntk_i[b * L_ + tid], pc & 0xFFFF);
        int old = atomicMin(&firstIdx[b * L_ + tid], sM1[tid]);
        atomicMin(&secondIdx[b * L_ + tid], max(old, sM1[tid]));
        atomicMin(&secondIdx[b * L_ + tid], sM2[tid]);
    }
    if (tid >= D_ && tid < L_ * D_)
        gatom_add(&sumemb[b * L_ * D_ + tid], sSum[tid]);
}

// ---------------------------------------------------------------------------
// K3: l_agg — reads emb + packed labels only; 9 loads straight-line +
// sched_barrier for full MLP; single scalar accumulator (val * 1/cntf[lf]).
// ---------------------------------------------------------------------------
__global__ __launch_bounds__(BLOCK, 2) void k_pass3(
        const float* __restrict__ emb, const unsigned int* __restrict__ lblpack,
        const int* __restrict__ firstIdx, const int* __restrict__ secondIdx,
        const int* __restrict__ cntk_i, const int* __restrict__ cntf_i,
        const float* __restrict__ sumemb, float* __restrict__ sumvalb) {
    __shared__ float4 sMean[L_];
    __shared__ float  sCd[L_], sInv[L_];
    __shared__ float  sAcc;

    const int tid = threadIdx.x;
    const int b   = blockIdx.y;

    if (tid < L_) {
        float4 mu = {0.f, 0.f, 0.f, 0.f};
        float cd = 0.f, inv = 0.f;
        if (tid > 0) {
            const float invk = 1.0f / fmaxf((float)cntk_i[b * L_ + tid], 1.0f);
            mu.x = sumemb[b * L_ * D_ + tid * D_ + 0] * invk;
            mu.y = sumemb[b * L_ * D_ + tid * D_ + 1] * invk;
            mu.z = sumemb[b * L_ * D_ + tid * D_ + 2] * invk;
            mu.w = sumemb[b * L_ * D_ + tid * D_ + 3] * invk;
            const float diag = sqrtf((float)(H_ * H_ + W_ * W_));
            int f = min(firstIdx[b * L_ + tid],  HW_ - 1);
            int s = min(secondIdx[b * L_ + tid], HW_ - 1);
            float r0 = (float)(f / W_), c0 = (float)(f % W_);
            float r1 = (float)(s / W_), c1 = (float)(s % W_);
            cd = __expf(sqrtf((r0 - c0) * (r0 - c0) + (r1 - c1) * (r1 - c1))
                        / diag * 0.5f);
            inv = 1.0f / fmaxf((float)cntf_i[b * L_ + tid], 1.0f);
        }
        sMean[tid] = mu; sCd[tid] = cd; sInv[tid] = inv;
        if (tid == 0) sAcc = 0.f;
    }
    __syncthreads();

    const int blockbase = blockIdx.x * PXB;
    const float* embb = emb + (size_t)b * D_ * HW_;
    const int o0 = blockbase + tid * 4;
    const int o1 = o0 + BLOCK * 4;

    // ---- 9 loads straight-line ----
    const unsigned int lp = lblpack[(size_t)(b * GRIDX + blockIdx.x) * BLOCK + tid];
    const float4 e00 = *(const float4*)(embb + 0 * HW_ + o0);
    const float4 e01 = *(const float4*)(embb + 1 * HW_ + o0);
    const float4 e02 = *(const float4*)(embb + 2 * HW_ + o0);
    const float4 e03 = *(const float4*)(embb + 3 * HW_ + o0);
    const float4 e10 = *(const float4*)(embb + 0 * HW_ + o1);
    const float4 e11 = *(const float4*)(embb + 1 * HW_ + o1);
    const float4 e12 = *(const float4*)(embb + 2 * HW_ + o1);
    const float4 e13 = *(const float4*)(embb + 3 * HW_ + o1);
    __builtin_amdgcn_sched_barrier(0);

    float acc = 0.f;
    {   // half 0
        const float* e0A = (const float*)&e00;
        const float* e1A = (const float*)&e01;
        const float* e2A = (const float*)&e02;
        const float* e3A = (const float*)&e03;
        #pragma unroll
        for (int c = 0; c < 4; ++c) {
            const int lf = (int)((lp >> (4 * c)) & 7u);
            const float4 mu = sMean[lf];
            float dx = e0A[c] - mu.x, dy = e1A[c] - mu.y;
            float dz = e2A[c] - mu.z, dw = e3A[c] - mu.w;
            float d2 = dx * dx + dy * dy + dz * dz + dw * dw;
            float x  = fmaxf(sCd[lf] * sqrtf(d2) - 0.5f, 0.0f);  // lf==0 -> 0
            acc += __logf(x * x + 1.0f) * sInv[lf];
        }
    }
    {   // half 1
        const float* e0A = (const float*)&e10;
        const float* e1A = (const float*)&e11;
        const float* e2A = (const float*)&e12;
        const float* e3A = (const float*)&e13;
        #pragma unroll
        for (int c = 0; c < 4; ++c) {
            const int lf = (int)((lp >> (4 * (4 + c))) & 7u);
            const float4 mu = sMean[lf];
            float dx = e0A[c] - mu.x, dy = e1A[c] - mu.y;
            float dz = e2A[c] - mu.z, dw = e3A[c] - mu.w;
            float d2 = dx * dx + dy * dy + dz * dz + dw * dw;
            float x  = fmaxf(sCd[lf] * sqrtf(d2) - 0.5f, 0.0f);
            acc += __logf(x * x + 1.0f) * sInv[lf];
        }
    }

    #pragma unroll
    for (int off = 32; off > 0; off >>= 1)
        acc += __shfl_down(acc, off);
    if ((tid & 63) == 0) atomicAdd(&sAcc, acc);
    __syncthreads();
    if (tid == 0) gatom_add(&sumvalb[b], sAcc);
}

// ---------------------------------------------------------------------------
// K4: parallel epilogue — one thread per (b, i, j) term.
// ---------------------------------------------------------------------------
__global__ __launch_bounds__(512) void k_final(
        const int* __restrict__ firstIdx, const int* __restrict__ secondIdx,
        const int* __restrict__ cntk_i, const float* __restrict__ sumemb,
        const float* __restrict__ sumvalb, float* __restrict__ out) {
    __shared__ float sWave[8];
    const int tid = threadIdx.x;
    const int b = tid >> 6, ij = tid & 63, i = ij >> 3, j = ij & 7;
    const float diag = sqrtf((float)(H_ * H_ + W_ * W_));

    float mi[D_], mj[D_];
    {
        float ci = 1.0f / fmaxf((float)cntk_i[b * L_ + i], 1.0f);
        float cj = 1.0f / fmaxf((float)cntk_i[b * L_ + j], 1.0f);
        #pragma unroll
        for (int d = 0; d < D_; ++d) {
            mi[d] = (i > 0) ? sumemb[(b * L_ + i) * D_ + d] * ci : 0.0f;
            mj[d] = (j > 0) ? sumemb[(b * L_ + j) * D_ + d] * cj : 0.0f;
        }
    }

    float contrib = 0.0f;
    if (j == 0) {            // l_reg term for label i (i=0 gives 0)
        float d2 = 0.f;
        #pragma unroll
        for (int d = 0; d < D_; ++d) d2 += mi[d] * mi[d];
        float n = (d2 > 0.f) ? sqrtf(d2) : 0.f;
        contrib += __logf(n + 1.0f) * (0.001f / (float)L_);
    }
    if (i == 0 && j == 1)    // l_agg (already /cntf per label)
        contrib += sumvalb[b] * (1.0f / (float)NL);
    if (i >= 1 && j >= 1 && i != j) {   // l_dis pair term
        float d2 = 0.f;
        #pragma unroll
        for (int d = 0; d < D_; ++d) {
            float df = mi[d] - mj[d];
            d2 += df * df;
        }
        float Dn = (d2 > 0.f) ? sqrtf(d2) : 0.f;
        int fi = min(firstIdx[b * L_ + i],  HW_ - 1);
        int si = min(secondIdx[b * L_ + i], HW_ - 1);
        int fj = min(firstIdx[b * L_ + j],  HW_ - 1);
        int sj = min(secondIdx[b * L_ + j], HW_ - 1);
        float ssi = (float)(fi / W_) + (float)(fi % W_);
        float tti = (float)(si / W_) + (float)(si % W_);
        float ssj = (float)(fj / W_) + (float)(fj % W_);
        float ttj = (float)(sj / W_) + (float)(sj % W_);
        float dx = ssi - ssj, dy = tti - ttj;
        float dp = sqrtf(dx * dx + dy * dy);
        float coef = 1.0f - 20.0f * __expf(-4.0f - 2.5f * dp / diag);
        float x = fmaxf(3.0f - coef * Dn, 0.0f);   // 2*delta_d = 3.0
        contrib += __logf(x * x + 1.0f) * (1.0f / 42.0f);
    }

    #pragma unroll
    for (int off = 32; off > 0; off >>= 1)
        contrib += __shfl_down(contrib, off);
    if ((tid & 63) == 0) sWave[tid >> 6] = contrib;
    __syncthreads();
    if (tid == 0) {
        float t = 0.f;
        #pragma unroll
        for (int w = 0; w < 8; ++w) t += sWave[w];
        out[0] = t * (1.0f / (float)B_);           // LOSS_WEIGHT = 1
    }
}

extern "C" void kernel_launch(void* const* d_in, const int* in_sizes, int n_in,
                              void* d_out, int out_size, void* d_ws, size_t ws_size,
                              hipStream_t stream) {
    const float* emb   = (const float*)d_in[0];
    const int*   inst  = (const int*)  d_in[1];
    const float* kern  = (const float*)d_in[2];
    const float* tmask = (const float*)d_in[3];
    // d_in[4] = bboxes, unused by the reference

    int*          ib        = (int*)d_ws;
    int*          firstIdx  = ib;
    int*          secondIdx = ib + 64;
    int*          cntf_i    = ib + 128;
    int*          cntk_i    = ib + 192;
    float*        sumemb    = (float*)(ib + 256);
    float*        sumvalb   = (float*)(ib + 512);
    unsigned int* lblpack   = (unsigned int*)(ib + 1024);
    float*        out       = (float*)d_out;

    dim3 grid(GRIDX, B_);   // (200, 8) = 1600 blocks

    k_init <<<1, 256, 0, stream>>>(ib);
    k_pass1<<<grid, BLOCK, 0, stream>>>(emb, inst, kern, tmask,
                                        firstIdx, secondIdx, cntf_i, cntk_i,
                                        sumemb, lblpack);
    k_pass3<<<grid, BLOCK, 0, stream>>>(emb, lblpack, firstIdx, secondIdx,
                                        cntk_i, cntf_i, sumemb, sumvalb);
    k_final<<<1, 512, 0, stream>>>(firstIdx, secondIdx, cntk_i,
                                   sumemb, sumvalb, out);
}